// Round 3
// baseline (33596.240 us; speedup 1.0000x reference)
//
#include <hip/hip_runtime.h>
#include <stdint.h>

typedef unsigned long long u64;
typedef uint32_t u32;

#define NPTS 50000
#define MCL  8334          // ceil(50000/6)
#define NITER 8333         // FPS steps after seed
#define INC 64
#define OUTC 128
#define FPS_G 49
#define FPS_T 1024
#define KCH 8              // knn N-chunks
#define CPTS 6250          // points per chunk
#define KTILE 250
#define NTILE 25
#define QBLK 33            // ceil(MCL/256)
#define RB 782             // ceil(NPTS/64) row-blocks for stats

// ---- ws byte offsets (total ~6.17 MB) ----
#define WS_SLOTS 0u            // 2*64 u64
#define WS_IDS   1024u         // 8448 i32
#define WS_POSF4 34816u        // 50000 float4
#define WS_CAND  834816u       // 8334*64 u64
#define WS_COL   5101824u      // 8334*8 i32
#define WS_PSUM  5368512u      // 782*128 f32
#define WS_PSQ   5768896u      // 782*128 f32
#define WS_AB    6169280u      // alpha[128], beta[128]
#define WS_TOTAL 6170304u

#define OUT_POS   (MCL * OUTC)            // 1066752
#define OUT_BATCH (OUT_POS + MCL * 3)     // 1091754

// pack pos + precomputed ||p||^2 (exact np order: (x*x+y*y)+z*z, no FMA)
__global__ void k_prep(const float* __restrict__ pos, float4* __restrict__ posf4,
                       u64* __restrict__ slots) {
    int i = blockIdx.x * blockDim.x + threadIdx.x;
    if (blockIdx.x == 0 && threadIdx.x < 128) slots[threadIdx.x] = 0ull;
    if (i < NPTS) {
        float x = pos[3 * i], y = pos[3 * i + 1], z = pos[3 * i + 2];
        float pp = __fadd_rn(__fadd_rn(__fmul_rn(x, x), __fmul_rn(y, y)), __fmul_rn(z, z));
        posf4[i] = make_float4(x, y, z, pp);
    }
}

// Exact FPS. 49 persistent blocks, 1 point/thread. Per iteration:
// local min_d update -> block max-key -> slot write -> all-to-all poll -> winner.
// key = (min_d_bits:32 | (0xFFFF-idx):16 | tag:16); u64-max == argmax with
// first-index tie-break (matches jnp.argmax).
__global__ void __launch_bounds__(FPS_T) k_fps(const float4* __restrict__ posf4,
                                               u64* __restrict__ slots,
                                               int* __restrict__ ids) {
    const int tid = threadIdx.x, bid = blockIdx.x;
    const int g = bid * FPS_T + tid;
    const bool act = g < NPTS;
    float px = 0.f, py = 0.f, pz = 0.f;
    if (act) { float4 p = posf4[g]; px = p.x; py = p.y; pz = p.z; }
    float md = act ? 1e10f : 0.0f;     // BIG sentinel, f32 like reference
    const u32 inv16 = act ? (0xFFFFu - (u32)g) : 0u;
    const int lane = tid & 63, wid = tid >> 6;
    __shared__ u64 wred[16];
    __shared__ u64 swin;
    int cur = 0;
    if (bid == 0 && tid == 0) ids[0] = 0;
    for (int it = 0; it < NITER; ++it) {
        const u64 tag = (u64)(it + 1);
        const int row = (it & 1) << 6;
        float4 w = posf4[cur];   // uniform address
        // exact np arithmetic: ((dx*dx+dy*dy)+dz*dz), rn ops, no contraction
        float dx = __fsub_rn(px, w.x), dy = __fsub_rn(py, w.y), dz = __fsub_rn(pz, w.z);
        float d = __fadd_rn(__fadd_rn(__fmul_rn(dx, dx), __fmul_rn(dy, dy)), __fmul_rn(dz, dz));
        md = fminf(md, d);  // inactive lanes: md stays 0
        u64 key = ((u64)__float_as_uint(md) << 32) | ((u64)inv16 << 16) | tag;
        #pragma unroll
        for (int o = 32; o >= 1; o >>= 1) {
            u64 other = __shfl_xor(key, o);
            if (other > key) key = other;
        }
        if (lane == 0) wred[wid] = key;
        __syncthreads();
        if (wid == 0) {
            u64 k2 = (lane < 16) ? wred[lane] : 0ull;
            #pragma unroll
            for (int o = 8; o >= 1; o >>= 1) {
                u64 other = __shfl_xor(k2, o);
                if (other > k2) k2 = other;
            }
            if (lane == 0)
                __hip_atomic_store(&slots[row + bid], k2, __ATOMIC_RELEASE, __HIP_MEMORY_SCOPE_AGENT);
            u64 v = 0ull;
            if (lane < FPS_G) {
                const u64* sp = &slots[row + lane];
                do {
                    v = __hip_atomic_load(sp, __ATOMIC_ACQUIRE, __HIP_MEMORY_SCOPE_AGENT);
                } while ((v & 0xFFFFull) != tag);
            }
            #pragma unroll
            for (int o = 32; o >= 1; o >>= 1) {
                u64 other = __shfl_xor(v, o);
                if (other > v) v = other;
            }
            if (lane == 0) swin = v;
        }
        __syncthreads();
        cur = 0xFFFF - (int)((swin >> 16) & 0xFFFFull);
        if (bid == 0 && tid == 0) ids[it + 1] = cur;
    }
}

// sub_pos + sub_batch outputs
__global__ void k_subs(const float* __restrict__ pos, const int* __restrict__ batch,
                       const int* __restrict__ ids, float* __restrict__ out) {
    int m = blockIdx.x * blockDim.x + threadIdx.x;
    if (m < MCL) {
        int id = ids[m];
        out[OUT_POS + m * 3 + 0] = pos[id * 3 + 0];
        out[OUT_POS + m * 3 + 1] = pos[id * 3 + 1];
        out[OUT_POS + m * 3 + 2] = pos[id * 3 + 2];
        out[OUT_BATCH + m] = (float)batch[id];  // zeros in this problem
    }
}

__device__ __forceinline__ u32 f2sort(float d) {
    u32 u = __float_as_uint(d);
    return (u & 0x80000000u) ? ~u : (u | 0x80000000u);
}

// per-(query-block, chunk) partial top-8 by (d, idx) lex key
__global__ void __launch_bounds__(256) k_knn(const float4* __restrict__ posf4,
                                             const int* __restrict__ ids,
                                             u64* __restrict__ cand) {
    __shared__ float4 tile[KTILE];
    const int bid = blockIdx.x, tid = threadIdx.x;
    const int qb = bid % QBLK, chunk = bid / QBLK;
    const int q = qb * 256 + tid;
    const bool act = q < MCL;
    float qx = 0.f, qy = 0.f, qz = 0.f, qq = 0.f;
    if (act) { float4 p = posf4[ids[q]]; qx = p.x; qy = p.y; qz = p.z; qq = p.w; }
    u64 r[8];
    #pragma unroll
    for (int j = 0; j < 8; ++j) r[j] = ~0ull;
    const int base0 = chunk * CPTS;
    for (int t = 0; t < NTILE; ++t) {
        __syncthreads();
        if (tid < KTILE) tile[tid] = posf4[base0 + t * KTILE + tid];
        __syncthreads();
        if (act) {
            for (int p = 0; p < KTILE; ++p) {
                float4 f = tile[p];
                // BLAS sgemm K=3 rounding: acc=fma(a0,b0,0); acc=fma(a1,b1,acc);
                // acc=fma(a2,b2,acc). fma(a,b,0)==rn(a*b).
                float c = __fmul_rn(qx, f.x);
                c = fmaf(qy, f.y, c);
                c = fmaf(qz, f.z, c);
                // ref formula eval order: (qq - 2*c) + pp, rn ops
                float d = __fadd_rn(__fsub_rn(qq, __fmul_rn(2.0f, c)), f.w);
                u64 key = ((u64)f2sort(d) << 32) | (u32)(base0 + t * KTILE + p);
                if (key < r[7]) {
                    r[7] = key;
                    #pragma unroll
                    for (int jj = 7; jj >= 1; --jj) {
                        if (r[jj] < r[jj - 1]) { u64 tk = r[jj]; r[jj] = r[jj - 1]; r[jj - 1] = tk; }
                    }
                }
            }
        }
    }
    if (act) {
        #pragma unroll
        for (int j = 0; j < 8; ++j) cand[(size_t)q * 64 + chunk * 8 + j] = r[j];
    }
}

__global__ void k_merge(const u64* __restrict__ cand, int* __restrict__ col) {
    int q = blockIdx.x * blockDim.x + threadIdx.x;
    if (q >= MCL) return;
    u64 r[8];
    #pragma unroll
    for (int j = 0; j < 8; ++j) r[j] = ~0ull;
    for (int k = 0; k < 64; ++k) {
        u64 key = cand[(size_t)q * 64 + k];
        if (key < r[7]) {
            r[7] = key;
            #pragma unroll
            for (int jj = 7; jj >= 1; --jj) {
                if (r[jj] < r[jj - 1]) { u64 tk = r[jj]; r[jj] = r[jj - 1]; r[jj - 1] = tk; }
            }
        }
    }
    #pragma unroll
    for (int j = 0; j < 8; ++j) col[q * 8 + j] = (int)(r[j] & 0xFFFFFFFFull);
}

// Linear(64->128) per-channel sum / sumsq partials (64 rows per block)
__global__ void __launch_bounds__(256) k_linstats(const float* __restrict__ x,
                                                  const float* __restrict__ w,
                                                  const float* __restrict__ b,
                                                  float* __restrict__ psum,
                                                  float* __restrict__ psq) {
    __shared__ float xs[64 * 65];
    __shared__ float ws[128 * 65];
    const int bid = blockIdx.x, tid = threadIdx.x;
    const int row0 = bid * 64;
    for (int idx = tid; idx < 64 * 64; idx += 256) {
        int r = idx >> 6, j = idx & 63;
        int gr = row0 + r;
        xs[r * 65 + j] = (gr < NPTS) ? x[gr * 64 + j] : 0.0f;
    }
    for (int idx = tid; idx < 128 * 64; idx += 256) {
        int c = idx >> 6, j = idx & 63;
        ws[c * 65 + j] = w[idx];
    }
    __syncthreads();
    const int ch = tid & 127, grp = tid >> 7;
    const float lb = b[ch];
    float s = 0.f, sq = 0.f;
    for (int rr = 0; rr < 32; ++rr) {
        int r = grp * 32 + rr;
        float acc = lb;
        #pragma unroll 8
        for (int j = 0; j < 64; ++j) acc = fmaf(xs[r * 65 + j], ws[ch * 65 + j], acc);
        if (row0 + r < NPTS) { s += acc; sq = fmaf(acc, acc, sq); }
    }
    __syncthreads();
    float* red = xs;  // reuse
    red[grp * 128 + ch] = s;
    red[256 + grp * 128 + ch] = sq;
    __syncthreads();
    if (grp == 0) {
        psum[bid * 128 + ch] = red[ch] + red[128 + ch];
        psq[bid * 128 + ch] = red[256 + ch] + red[256 + 128 + ch];
    }
}

// mean/var -> per-channel affine (alpha, beta); folds GraphNorm
__global__ void k_finalize(const float* __restrict__ psum, const float* __restrict__ psq,
                           const float* __restrict__ gnw, const float* __restrict__ gnb,
                           const float* __restrict__ gms, float* __restrict__ ab) {
    int ch = threadIdx.x;  // 128 threads
    float s = 0.f, q = 0.f;
    for (int bk = 0; bk < RB; ++bk) { s += psum[bk * 128 + ch]; q += psq[bk * 128 + ch]; }
    float m = s / (float)NPTS;
    float e2 = q / (float)NPTS;
    float msc = gms[ch];
    float mm = msc * m;
    float var = e2 - 2.0f * mm * m + mm * mm;
    float inv = rsqrtf(var + 1e-5f);
    float a = inv * gnw[ch];
    ab[ch] = a;
    ab[128 + ch] = gnb[ch] - mm * a;
}

// recompute h rows for the 8 neighbors, max/min, affine+relu, write out
__global__ void __launch_bounds__(128) k_gather(const float* __restrict__ x,
                                                const float* __restrict__ w,
                                                const float* __restrict__ b,
                                                const int* __restrict__ col,
                                                const float* __restrict__ ab,
                                                float* __restrict__ out) {
    __shared__ float xs[8 * 64];
    __shared__ float ws[128 * 65];
    __shared__ int cl[8];
    const int m = blockIdx.x, tid = threadIdx.x;
    if (tid < 8) cl[tid] = col[m * 8 + tid];
    __syncthreads();
    for (int idx = tid; idx < 512; idx += 128) {
        int r = idx >> 6, j = idx & 63;
        xs[idx] = x[cl[r] * 64 + j];
    }
    for (int idx = tid; idx < 128 * 64; idx += 128) {
        int c = idx >> 6, j = idx & 63;
        ws[c * 65 + j] = w[idx];
    }
    __syncthreads();
    const int ch = tid;
    const float lb = b[ch];
    float hmax = -3.402823466e38f, hmin = 3.402823466e38f;
    #pragma unroll
    for (int r = 0; r < 8; ++r) {
        float acc = lb;
        #pragma unroll 8
        for (int j = 0; j < 64; ++j) acc = fmaf(xs[r * 64 + j], ws[ch * 65 + j], acc);
        hmax = fmaxf(hmax, acc);
        hmin = fminf(hmin, acc);
    }
    float a = ab[ch], be = ab[128 + ch];
    float v = (a >= 0.0f) ? hmax : hmin;   // max/affine commute per sign
    out[m * OUTC + ch] = fmaxf(0.0f, fmaf(a, v, be));
}

extern "C" void kernel_launch(void* const* d_in, const int* in_sizes, int n_in,
                              void* d_out, int out_size, void* d_ws, size_t ws_size,
                              hipStream_t stream) {
    const float* x     = (const float*)d_in[0];
    const float* pos   = (const float*)d_in[1];
    const int*   batch = (const int*)d_in[2];
    const float* lin_w = (const float*)d_in[3];
    const float* lin_b = (const float*)d_in[4];
    const float* gnw   = (const float*)d_in[5];
    const float* gnb   = (const float*)d_in[6];
    const float* gms   = (const float*)d_in[7];
    float* out = (float*)d_out;

    if (ws_size < (size_t)WS_TOTAL) return;  // fail loudly via wrong output

    char* ws = (char*)d_ws;
    u64*    slots = (u64*)(ws + WS_SLOTS);
    int*    ids   = (int*)(ws + WS_IDS);
    float4* posf4 = (float4*)(ws + WS_POSF4);
    u64*    cand  = (u64*)(ws + WS_CAND);
    int*    col   = (int*)(ws + WS_COL);
    float*  psum  = (float*)(ws + WS_PSUM);
    float*  psq   = (float*)(ws + WS_PSQ);
    float*  ab    = (float*)(ws + WS_AB);

    k_prep<<<196, 256, 0, stream>>>(pos, posf4, slots);
    k_fps<<<FPS_G, FPS_T, 0, stream>>>(posf4, slots, ids);
    k_subs<<<QBLK, 256, 0, stream>>>(pos, batch, ids, out);
    k_knn<<<QBLK * KCH, 256, 0, stream>>>(posf4, ids, cand);
    k_merge<<<QBLK, 256, 0, stream>>>(cand, col);
    k_linstats<<<RB, 256, 0, stream>>>(x, lin_w, lin_b, psum, psq);
    k_finalize<<<1, 128, 0, stream>>>(psum, psq, gnw, gnb, gms, ab);
    k_gather<<<MCL, 128, 0, stream>>>(x, lin_w, lin_b, col, ab, out);
}